// Round 5
// baseline (1458.611 us; speedup 1.0000x reference)
//
#include <hip/hip_runtime.h>

#define B_  4
#define L_  1024
#define D_  512
#define H_  8
#define DK_ 64
#define BL_ (B_*L_)

typedef unsigned short us16;   // raw bf16 bits

__device__ __forceinline__ float us2f(us16 u) {
  union { unsigned int i; float f; } x;
  x.i = ((unsigned int)u) << 16;
  return x.f;
}
__device__ __forceinline__ us16 f2us(float f) {
  union { float f; unsigned int i; } x;
  x.f = f;
  unsigned int r = x.i + 0x7FFFu + ((x.i >> 16) & 1u);  // RNE
  return (us16)(r >> 16);
}

#define BM 64
#define BN 64
#define BK 16

// C(bf16 ws, M x 512) = A(f32) @ W(f32) + bias(f32)
__global__ __launch_bounds__(256) void gemm_f32(
    const float* __restrict__ A, const float* __restrict__ W,
    const float* __restrict__ bias, us16* __restrict__ C) {
  __shared__ float As[BK][BM + 1];
  __shared__ float Bs[BK][BN + 1];
  const int tid = threadIdx.x;
  const int tx = tid & 15, ty = tid >> 4;
  const int row0 = blockIdx.y * BM, col0 = blockIdx.x * BN;
  float acc[4][4] = {};
  for (int k0 = 0; k0 < D_; k0 += BK) {
    for (int i = tid; i < BM * BK; i += 256) {
      int r = i >> 4, c = i & 15;
      As[c][r] = A[(size_t)(row0 + r) * D_ + k0 + c];
    }
    for (int i = tid; i < BK * BN; i += 256) {
      int r = i >> 6, c = i & 63;
      Bs[r][c] = W[(size_t)(k0 + r) * D_ + col0 + c];
    }
    __syncthreads();
#pragma unroll
    for (int kk = 0; kk < BK; ++kk) {
      float a[4], bb[4];
#pragma unroll
      for (int i = 0; i < 4; ++i) a[i] = As[kk][ty * 4 + i];
#pragma unroll
      for (int j = 0; j < 4; ++j) bb[j] = Bs[kk][tx * 4 + j];
#pragma unroll
      for (int i = 0; i < 4; ++i)
#pragma unroll
        for (int j = 0; j < 4; ++j) acc[i][j] += a[i] * bb[j];
    }
    __syncthreads();
  }
#pragma unroll
  for (int i = 0; i < 4; ++i) {
    int r = row0 + ty * 4 + i;
#pragma unroll
    for (int j = 0; j < 4; ++j) {
      int c = col0 + tx * 4 + j;
      C[(size_t)r * D_ + c] = f2us(acc[i][j] + bias[c]);
    }
  }
}

// C(f32 FINAL OUT) = A(bf16 ws) @ W(f32) + bias(f32)
__global__ __launch_bounds__(256) void gemm_dense(
    const us16* __restrict__ A, const float* __restrict__ W,
    const float* __restrict__ bias, float* __restrict__ C) {
  __shared__ float As[BK][BM + 1];
  __shared__ float Bs[BK][BN + 1];
  const int tid = threadIdx.x;
  const int tx = tid & 15, ty = tid >> 4;
  const int row0 = blockIdx.y * BM, col0 = blockIdx.x * BN;
  float acc[4][4] = {};
  for (int k0 = 0; k0 < D_; k0 += BK) {
    for (int i = tid; i < BM * BK; i += 256) {
      int r = i >> 4, c = i & 15;
      As[c][r] = us2f(A[(size_t)(row0 + r) * D_ + k0 + c]);
    }
    for (int i = tid; i < BK * BN; i += 256) {
      int r = i >> 6, c = i & 63;
      Bs[r][c] = W[(size_t)(k0 + r) * D_ + col0 + c];
    }
    __syncthreads();
#pragma unroll
    for (int kk = 0; kk < BK; ++kk) {
      float a[4], bb[4];
#pragma unroll
      for (int i = 0; i < 4; ++i) a[i] = As[kk][ty * 4 + i];
#pragma unroll
      for (int j = 0; j < 4; ++j) bb[j] = Bs[kk][tx * 4 + j];
#pragma unroll
      for (int i = 0; i < 4; ++i)
#pragma unroll
        for (int j = 0; j < 4; ++j) acc[i][j] += a[i] * bb[j];
    }
    __syncthreads();
  }
#pragma unroll
  for (int i = 0; i < 4; ++i) {
    int r = row0 + ty * 4 + i;
#pragma unroll
    for (int j = 0; j < 4; ++j) {
      int c = col0 + tx * 4 + j;
      C[(size_t)r * D_ + c] = acc[i][j] + bias[c];
    }
  }
}

// m[b,q,k] = sigmoid(dot(QP[b,q,:], KP[b,k,:]) / sqrt(512)) -> f32 (d_out m region)
__global__ __launch_bounds__(256) void mask_gemm(
    const us16* __restrict__ QP, const us16* __restrict__ KP,
    float* __restrict__ Mout) {
  __shared__ float As[BK][BM + 1];
  __shared__ float Bs[BK][BM + 1];
  const int tid = threadIdx.x;
  const int tx = tid & 15, ty = tid >> 4;
  const int b = blockIdx.z;
  const int row0 = blockIdx.y * BM, col0 = blockIdx.x * BM;
  const us16* Ab = QP + (size_t)b * L_ * D_;
  const us16* Bb = KP + (size_t)b * L_ * D_;
  float acc[4][4] = {};
  for (int k0 = 0; k0 < D_; k0 += BK) {
    for (int i = tid; i < 64 * 16; i += 256) {
      int r = i >> 4, c = i & 15;
      As[c][r] = us2f(Ab[(size_t)(row0 + r) * D_ + k0 + c]);
      Bs[c][r] = us2f(Bb[(size_t)(col0 + r) * D_ + k0 + c]);
    }
    __syncthreads();
#pragma unroll
    for (int kk = 0; kk < BK; ++kk) {
      float a[4], bb[4];
#pragma unroll
      for (int i = 0; i < 4; ++i) a[i] = As[kk][ty * 4 + i];
#pragma unroll
      for (int j = 0; j < 4; ++j) bb[j] = Bs[kk][tx * 4 + j];
#pragma unroll
      for (int i = 0; i < 4; ++i)
#pragma unroll
        for (int j = 0; j < 4; ++j) acc[i][j] += a[i] * bb[j];
    }
    __syncthreads();
  }
  const float sc = 0.04419417382415922f;  // 1/sqrt(512)
#pragma unroll
  for (int i = 0; i < 4; ++i) {
    int q = row0 + ty * 4 + i;
#pragma unroll
    for (int j = 0; j < 4; ++j) {
      int k = col0 + tx * 4 + j;
      float x = acc[i][j] * sc;
      Mout[((size_t)b * L_ + q) * L_ + k] = 1.f / (1.f + __expf(-x));
    }
  }
}

// One wave per query row; full score row in LDS; exact double softmax.
// Gate fused (reads raw f32 query). O aliases Q (in-place): each block reads
// only its own (row, head) Q cells before writing them -> safe.
__global__ __launch_bounds__(256) void attn_kernel(
    const us16* Q, const us16* __restrict__ K,
    const us16* __restrict__ V, const float* __restrict__ Mm,
    const float* __restrict__ query, const float* __restrict__ gw,
    const float* __restrict__ gb, us16* O) {
  __shared__ float sbuf[4][L_];
  __shared__ float qbuf[4][DK_];
  const int w = threadIdx.x >> 6, lane = threadIdx.x & 63;
  const int b = blockIdx.z, h = blockIdx.y;
  const int q = blockIdx.x * 4 + w;
  const size_t rowq = (size_t)b * L_ + q;

  qbuf[w][lane] = us2f(Q[rowq * D_ + h * DK_ + lane]);

  // fused gate: gq = sigmoid(query[rowq,:] . gw + gb)
  float gp = 0.f;
#pragma unroll
  for (int d0 = 0; d0 < D_; d0 += 64)
    gp += query[rowq * D_ + d0 + lane] * gw[d0 + lane];
#pragma unroll
  for (int off = 32; off; off >>= 1) gp += __shfl_down(gp, off);
  float gq = __shfl(gp, 0);
  gq = 1.f / (1.f + __expf(-(gq + gb[0])));
  __syncthreads();

  // phase 1: scores
  const us16* Kh = K + (size_t)b * L_ * D_ + h * DK_;
  float mx = -1e30f;
  for (int k0 = 0; k0 < L_; k0 += 64) {
    const ushort4* K4 = (const ushort4*)(Kh + (size_t)(k0 + lane) * D_);
    float s = 0.f;
#pragma unroll
    for (int d4 = 0; d4 < 16; ++d4) {
      ushort4 kv = K4[d4];
      s += qbuf[w][4 * d4 + 0] * us2f(kv.x) + qbuf[w][4 * d4 + 1] * us2f(kv.y) +
           qbuf[w][4 * d4 + 2] * us2f(kv.z) + qbuf[w][4 * d4 + 3] * us2f(kv.w);
    }
    s *= 0.125f;  // 1/sqrt(64)
    sbuf[w][k0 + lane] = s;
    mx = fmaxf(mx, s);
  }
#pragma unroll
  for (int off = 32; off; off >>= 1) mx = fmaxf(mx, __shfl_down(mx, off));
  mx = __shfl(mx, 0);

  // phase 2: first-softmax numerators + sum
  float sum = 0.f;
  for (int k = lane; k < L_; k += 64) {
    float e = __expf(sbuf[w][k] - mx);
    sbuf[w][k] = e;
    sum += e;
  }
#pragma unroll
  for (int off = 32; off; off >>= 1) sum += __shfl_down(sum, off);
  sum = __shfl(sum, 0);
  float inv = 1.f / sum;

  // phase 3: comb = p * (g + (1-g)*exp(1-m))
  const float* mrow = Mm + rowq * L_;
  float mx2 = -1e30f;
  for (int k = lane; k < L_; k += 64) {
    float p = sbuf[w][k] * inv;
    float wk = gq + (1.f - gq) * __expf(1.f - mrow[k]);
    float c = p * wk;
    sbuf[w][k] = c;
    mx2 = fmaxf(mx2, c);
  }
#pragma unroll
  for (int off = 32; off; off >>= 1) mx2 = fmaxf(mx2, __shfl_down(mx2, off));
  mx2 = __shfl(mx2, 0);

  // phase 4: second-softmax numerators + sum
  float sum2 = 0.f;
  for (int k = lane; k < L_; k += 64) {
    float e = __expf(sbuf[w][k] - mx2);
    sbuf[w][k] = e;
    sum2 += e;
  }
#pragma unroll
  for (int off = 32; off; off >>= 1) sum2 += __shfl_down(sum2, off);
  sum2 = __shfl(sum2, 0);
  float inv2 = 1.f / sum2;

  // phase 5: out_row[d=lane] = sum_k attn[k] * V[k][d]
  const us16* Vh = V + (size_t)b * L_ * D_ + h * DK_;
  float a0 = 0.f, a1 = 0.f, a2 = 0.f, a3 = 0.f;
  for (int k = 0; k < L_; k += 4) {
    a0 += sbuf[w][k + 0] * us2f(Vh[(size_t)(k + 0) * D_ + lane]);
    a1 += sbuf[w][k + 1] * us2f(Vh[(size_t)(k + 1) * D_ + lane]);
    a2 += sbuf[w][k + 2] * us2f(Vh[(size_t)(k + 2) * D_ + lane]);
    a3 += sbuf[w][k + 3] * us2f(Vh[(size_t)(k + 3) * D_ + lane]);
  }
  float acc = (a0 + a1) + (a2 + a3);
  O[rowq * D_ + h * DK_ + lane] = f2us(acc * inv2);
}

extern "C" void kernel_launch(void* const* d_in, const int* in_sizes, int n_in,
                              void* d_out, int out_size, void* d_ws, size_t ws_size,
                              hipStream_t stream) {
  const float* query   = (const float*)d_in[0];
  const float* key     = (const float*)d_in[1];
  const float* value   = (const float*)d_in[2];
  const float* wq_w    = (const float*)d_in[3];
  const float* wq_b    = (const float*)d_in[4];
  const float* wk_w    = (const float*)d_in[5];
  const float* wk_b    = (const float*)d_in[6];
  const float* wv_w    = (const float*)d_in[7];
  const float* wv_b    = (const float*)d_in[8];
  const float* dense_w = (const float*)d_in[9];
  const float* dense_b = (const float*)d_in[10];
  const float* gate_w  = (const float*)d_in[11];
  const float* gate_b  = (const float*)d_in[12];
  const float* mp_wq_w = (const float*)d_in[13];
  const float* mp_wq_b = (const float*)d_in[14];
  const float* mp_wk_w = (const float*)d_in[15];
  const float* mp_wk_b = (const float*)d_in[16];

  const size_t RSZ = (size_t)BL_ * D_;  // 2,097,152 elems; bf16 region = 4 MB
  us16* R0 = (us16*)d_ws;               // ws use: exactly 8 MB
  us16* R1 = R0 + RSZ;

  float* out0 = (float*)d_out;                 // final out (B,L,D) f32 = 8 MB
  float* outm = out0 + (size_t)B_ * L_ * D_;   // m (B,L,L) f32 = 16 MB
  us16* Vstage = (us16*)d_out;                 // V staged bf16 in out region (4 MB),
                                               // dead before dense overwrites it

  dim3 blk(256);
  dim3 gproj(D_ / BN, BL_ / BM);  // (8, 64)

  // Mask-perturbation projections + mask (R0/R1 reused afterwards).
  hipLaunchKernelGGL(gemm_f32, gproj, blk, 0, stream, query, mp_wq_w, mp_wq_b, R0);
  hipLaunchKernelGGL(gemm_f32, gproj, blk, 0, stream, key,   mp_wk_w, mp_wk_b, R1);
  hipLaunchKernelGGL(mask_gemm, dim3(L_ / 64, L_ / 64, B_), blk, 0, stream, R0, R1, outm);
  // Q/K/V projections: Q->R0, K->R1, V->Vstage (bf16, in out region).
  hipLaunchKernelGGL(gemm_f32, gproj, blk, 0, stream, query, wq_w, wq_b, R0);
  hipLaunchKernelGGL(gemm_f32, gproj, blk, 0, stream, key,   wk_w, wk_b, R1);
  hipLaunchKernelGGL(gemm_f32, gproj, blk, 0, stream, value, wv_w, wv_b, Vstage);
  // Attention: gate fused; O written in place over Q (R0); m read f32.
  hipLaunchKernelGGL(attn_kernel, dim3(L_ / 4, H_, B_), blk, 0, stream,
                     R0, R1, Vstage, outm, query, gate_w, gate_b, R0);
  // Final dense: reads attn output (R0), writes f32 out (overwrites Vstage area).
  hipLaunchKernelGGL(gemm_dense, gproj, blk, 0, stream, R0, dense_w, dense_b, out0);
}

// Round 6
// 328.375 us; speedup vs baseline: 4.4419x; 4.4419x over previous
//
#include <hip/hip_runtime.h>

#define B_  4
#define L_  1024
#define D_  512
#define H_  8
#define DK_ 64
#define BL_ (B_*L_)

typedef unsigned short us16;   // raw bf16 bits
typedef __attribute__((ext_vector_type(8))) short bf16x8;
typedef __attribute__((ext_vector_type(4))) float f32x4;

__device__ __forceinline__ float us2f(us16 u) {
  union { unsigned int i; float f; } x;
  x.i = ((unsigned int)u) << 16;
  return x.f;
}
__device__ __forceinline__ us16 f2us(float f) {
  union { float f; unsigned int i; } x;
  x.f = f;
  unsigned int r = x.i + 0x7FFFu + ((x.i >> 16) & 1u);  // RNE
  return (us16)(r >> 16);
}
__device__ __forceinline__ us16 cvt_us(float f) { return f2us(f); }
__device__ __forceinline__ us16 cvt_us(us16 u) { return u; }

#define MFMA(a, b, c) __builtin_amdgcn_mfma_f32_16x16x32_bf16(a, b, c, 0, 0, 0)

// ---------------------------------------------------------------------------
// Generic 64x64-tile MFMA GEMM: C = A(M x 512) @ W(512 x 512) + bias.
// MODE 0: C bf16 row-major [.][512] (ws intermediates)
// MODE 1: C bf16 transposed per-head [b][h][dk][kv] (V for PV B-frags)
// MODE 2: C f32 row-major (final out)
// TA: float (raw inputs) or us16 (bf16 ws).
// ---------------------------------------------------------------------------
template <int MODE, typename TA>
__global__ __launch_bounds__(256) void gemm16(
    const TA* __restrict__ A, const float* __restrict__ W,
    const float* __restrict__ bias, void* __restrict__ Cout) {
  __shared__ us16 Al[64][56];   // [row][k], stride 112 B (16B-mult for b128)
  __shared__ us16 Wl[64][56];   // transposed [n][k]
  const int tid = threadIdx.x;
  const int w = tid >> 6, lane = tid & 63;
  const int quad = lane >> 4, lc = lane & 15;
  const int row0 = blockIdx.y * 64, col0 = blockIdx.x * 64;
  f32x4 acc[4] = {};                       // wave w: rows [row0+16w, +16), 4 col-tiles
  const int arow = tid >> 2, aks = (tid & 3) * 8;   // A stage: 64 rows x 4 k-octets
  const int wk = tid & 31, wns = (tid >> 5) * 8;    // W stage: 32 k x 8 n-octets

  for (int k0 = 0; k0 < 512; k0 += 32) {
    {  // stage A -> bf16 LDS (b128 write)
      union { bf16x8 v; us16 u[8]; } pk;
      const TA* src = A + (size_t)(row0 + arow) * 512 + k0 + aks;
#pragma unroll
      for (int j = 0; j < 8; ++j) pk.u[j] = cvt_us(src[j]);
      *(bf16x8*)&Al[arow][aks] = pk.v;
    }
    {  // stage W transposed [n][k]
      const float* src = W + (size_t)(k0 + wk) * 512 + col0 + wns;
#pragma unroll
      for (int j = 0; j < 8; ++j) Wl[wns + j][wk] = f2us(src[j]);
    }
    __syncthreads();
    bf16x8 af = *(const bf16x8*)&Al[w * 16 + lc][quad * 8];
#pragma unroll
    for (int ct = 0; ct < 4; ++ct) {
      bf16x8 bf = *(const bf16x8*)&Wl[ct * 16 + lc][quad * 8];
      acc[ct] = MFMA(af, bf, acc[ct]);
    }
    __syncthreads();
  }

  const int orow = row0 + w * 16 + quad * 4;
#pragma unroll
  for (int ct = 0; ct < 4; ++ct) {
    const int col = col0 + ct * 16 + lc;
    const float bv = bias[col];
    if (MODE == 0) {
      us16* C = (us16*)Cout;
#pragma unroll
      for (int r = 0; r < 4; ++r)
        C[(size_t)(orow + r) * 512 + col] = f2us(acc[ct][r] + bv);
    } else if (MODE == 1) {
      us16* C = (us16*)Cout;
      const int h = col >> 6, dk = col & 63;
#pragma unroll
      for (int r = 0; r < 4; ++r) {
        const int grow = orow + r;
        const int b = grow >> 10, kv = grow & 1023;
        C[(((size_t)b * H_ + h) * DK_ + dk) * L_ + kv] = f2us(acc[ct][r] + bv);
      }
    } else {
      float* C = (float*)Cout;
#pragma unroll
      for (int r = 0; r < 4; ++r)
        C[(size_t)(orow + r) * 512 + col] = acc[ct][r] + bv;
    }
  }
}

// ---------------------------------------------------------------------------
// Mask: m[b,q,k] = sigmoid(QP[b,q,:].KP[b,k,:] / sqrt(512)), NT MFMA GEMM.
// ---------------------------------------------------------------------------
__global__ __launch_bounds__(256) void mask16(
    const us16* __restrict__ QP, const us16* __restrict__ KP,
    float* __restrict__ Mout) {
  __shared__ us16 Al[64][56];
  __shared__ us16 Bl[64][56];
  const int tid = threadIdx.x;
  const int w = tid >> 6, lane = tid & 63;
  const int quad = lane >> 4, lc = lane & 15;
  const int b = blockIdx.z;
  const int row0 = blockIdx.y * 64, col0 = blockIdx.x * 64;
  const us16* Ab = QP + (size_t)b * L_ * D_;
  const us16* Bb = KP + (size_t)b * L_ * D_;
  f32x4 acc[4] = {};
  const int arow = tid >> 2, aks = (tid & 3) * 8;
  for (int k0 = 0; k0 < 512; k0 += 32) {
    *(bf16x8*)&Al[arow][aks] =
        *(const bf16x8*)(Ab + (size_t)(row0 + arow) * 512 + k0 + aks);
    *(bf16x8*)&Bl[arow][aks] =
        *(const bf16x8*)(Bb + (size_t)(col0 + arow) * 512 + k0 + aks);
    __syncthreads();
    bf16x8 af = *(const bf16x8*)&Al[w * 16 + lc][quad * 8];
#pragma unroll
    for (int ct = 0; ct < 4; ++ct) {
      bf16x8 bf = *(const bf16x8*)&Bl[ct * 16 + lc][quad * 8];
      acc[ct] = MFMA(af, bf, acc[ct]);
    }
    __syncthreads();
  }
  const float sc = 0.04419417382415922f;  // 1/sqrt(512)
  const int orow = row0 + w * 16 + quad * 4;
#pragma unroll
  for (int ct = 0; ct < 4; ++ct) {
    const int col = col0 + ct * 16 + lc;
#pragma unroll
    for (int r = 0; r < 4; ++r) {
      float x = acc[ct][r] * sc;
      Mout[((size_t)b * L_ + orow + r) * L_ + col] = 1.f / (1.f + __expf(-x));
    }
  }
}

// g[row] = sigmoid(query[row,:] . gate_w + gate_b)
__global__ __launch_bounds__(256) void gate_kernel(
    const float* __restrict__ query, const float* __restrict__ gw,
    const float* __restrict__ gb, float* __restrict__ g) {
  int row = blockIdx.x * 4 + (threadIdx.x >> 6);
  int lane = threadIdx.x & 63;
  float p = 0.f;
  for (int d = lane; d < D_; d += 64) p += query[(size_t)row * D_ + d] * gw[d];
#pragma unroll
  for (int off = 32; off; off >>= 1) p += __shfl_down(p, off);
  if (lane == 0) g[row] = 1.f / (1.f + __expf(-(p + gb[0])));
}

// ---------------------------------------------------------------------------
// Fused attention per (16-q-strip, h, b): QK^T mfma -> S strip (16x1024 f32 LDS)
// -> exact double softmax (64 vals/thread in regs) -> P bf16 in-place ->
// PV mfma with V pre-transposed [b][h][dk][kv]. O written over Qp (safe).
// ---------------------------------------------------------------------------
__global__ __launch_bounds__(256) void attn16(
    const us16* Qp, const us16* __restrict__ Kp,
    const us16* __restrict__ Vt, const float* __restrict__ Mm,
    const float* __restrict__ gbuf, us16* O) {
  __shared__ us16 Ql[16][72];
  __shared__ float S[16][1040];   // also reused as P (bf16, stride 1040 us16)
  const int tid = threadIdx.x;
  const int w = tid >> 6, lane = tid & 63;
  const int quad = lane >> 4, lc = lane & 15;
  const int b = blockIdx.z, h = blockIdx.y, q0 = blockIdx.x * 16;

  if (tid < 128) {  // stage Q strip (16 x 64 bf16)
    int r = tid >> 3, ks = (tid & 7) * 8;
    *(bf16x8*)&Ql[r][ks] =
        *(const bf16x8*)(Qp + (size_t)(b * L_ + q0 + r) * D_ + h * DK_ + ks);
  }
  __syncthreads();

  bf16x8 qa0 = *(const bf16x8*)&Ql[lc][quad * 8];
  bf16x8 qa1 = *(const bf16x8*)&Ql[lc][32 + quad * 8];

  // QK^T: wave w covers cols kt*64 + w*16 + lc
  const us16* Kbase = Kp + (size_t)b * L_ * D_ + h * DK_;
  for (int kt = 0; kt < 16; ++kt) {
    const int kcol = kt * 64 + w * 16 + lc;
    const us16* kr = Kbase + (size_t)kcol * D_;
    bf16x8 b0 = *(const bf16x8*)(kr + quad * 8);
    bf16x8 b1 = *(const bf16x8*)(kr + 32 + quad * 8);
    f32x4 a = {};
    a = MFMA(qa0, b0, a);
    a = MFMA(qa1, b1, a);
#pragma unroll
    for (int r = 0; r < 4; ++r)
      S[quad * 4 + r][kt * 64 + w * 16 + lc] = a[r] * 0.125f;  // 1/sqrt(64)
  }
  __syncthreads();

  // double softmax: row = tid>>4, 16 threads per row, stride-16 cols
  const int row = tid >> 4, cs = tid & 15;
  float v[64];
#pragma unroll
  for (int i = 0; i < 64; ++i) v[i] = S[row][cs + 16 * i];
  float mx = -1e30f;
#pragma unroll
  for (int i = 0; i < 64; ++i) mx = fmaxf(mx, v[i]);
#pragma unroll
  for (int off = 1; off < 16; off <<= 1) mx = fmaxf(mx, __shfl_xor(mx, off));
  float sum = 0.f;
#pragma unroll
  for (int i = 0; i < 64; ++i) { v[i] = __expf(v[i] - mx); sum += v[i]; }
#pragma unroll
  for (int off = 1; off < 16; off <<= 1) sum += __shfl_xor(sum, off);
  const float inv = 1.f / sum;

  const float gq = gbuf[b * L_ + q0 + row];
  const float* mrow = Mm + (size_t)(b * L_ + q0 + row) * L_;
  float mx2 = -1e30f;
#pragma unroll
  for (int i = 0; i < 64; ++i) {
    float m = mrow[cs + 16 * i];
    float c = v[i] * inv * (gq + (1.f - gq) * __expf(1.f - m));
    v[i] = c;
    mx2 = fmaxf(mx2, c);
  }
#pragma unroll
  for (int off = 1; off < 16; off <<= 1) mx2 = fmaxf(mx2, __shfl_xor(mx2, off));
  float sum2 = 0.f;
#pragma unroll
  for (int i = 0; i < 64; ++i) { v[i] = __expf(v[i] - mx2); sum2 += v[i]; }
#pragma unroll
  for (int off = 1; off < 16; off <<= 1) sum2 += __shfl_xor(sum2, off);
  const float inv2 = 1.f / sum2;
  __syncthreads();  // all reads of S-as-f32 done

  // P (bf16) in place over S: P[r][c] at us16 index r*1040 + c
  us16* P = (us16*)&S[0][0];
#pragma unroll
  for (int i = 0; i < 64; ++i)
    P[row * 1040 + cs + 16 * i] = f2us(v[i] * inv2);
  __syncthreads();

  // PV: wave w computes O cols dk in [w*16, w*16+16)
  const us16* Vb = Vt + ((size_t)(b * H_ + h) * DK_) * L_;  // [dk][kv]
  f32x4 oacc = {};
  for (int kv = 0; kv < L_; kv += 32) {
    bf16x8 pa = *(const bf16x8*)&P[lc * 1040 + kv + quad * 8];
    bf16x8 vb = *(const bf16x8*)(Vb + (size_t)(w * 16 + lc) * L_ + kv + quad * 8);
    oacc = MFMA(pa, vb, oacc);
  }
#pragma unroll
  for (int r = 0; r < 4; ++r)
    O[(size_t)(b * L_ + q0 + quad * 4 + r) * D_ + h * DK_ + w * 16 + lc] =
        f2us(oacc[r]);
}

extern "C" void kernel_launch(void* const* d_in, const int* in_sizes, int n_in,
                              void* d_out, int out_size, void* d_ws, size_t ws_size,
                              hipStream_t stream) {
  const float* query   = (const float*)d_in[0];
  const float* key     = (const float*)d_in[1];
  const float* value   = (const float*)d_in[2];
  const float* wq_w    = (const float*)d_in[3];
  const float* wq_b    = (const float*)d_in[4];
  const float* wk_w    = (const float*)d_in[5];
  const float* wk_b    = (const float*)d_in[6];
  const float* wv_w    = (const float*)d_in[7];
  const float* wv_b    = (const float*)d_in[8];
  const float* dense_w = (const float*)d_in[9];
  const float* dense_b = (const float*)d_in[10];
  const float* gate_w  = (const float*)d_in[11];
  const float* gate_b  = (const float*)d_in[12];
  const float* mp_wq_w = (const float*)d_in[13];
  const float* mp_wq_b = (const float*)d_in[14];
  const float* mp_wk_w = (const float*)d_in[15];
  const float* mp_wk_b = (const float*)d_in[16];

  const size_t RSZ = (size_t)BL_ * D_;  // 2,097,152 elems; 4 MB bf16 per region
  us16* R0 = (us16*)d_ws;               // ws use: exactly 8 MB
  us16* R1 = R0 + RSZ;

  float* out0 = (float*)d_out;                 // final out (B,L,D) f32 (8 MB)
  float* outm = out0 + (size_t)B_ * L_ * D_;   // m (B,L,L) f32 (16 MB)
  us16*  Vt   = (us16*)d_out;                  // V^T staged bf16 in out bytes [0,4M)
  float* gbuf = (float*)((char*)d_out + (4u << 20));  // gate in out bytes [4M,4M+16K)

  dim3 blk(256);
  dim3 gproj(8, 64);       // 64x64 tiles over 4096x512
  dim3 gmask(16, 16, B_);  // 64x64 tiles over 1024x1024 x B
  dim3 gattn(L_ / 16, H_, B_);

  // Mask-perturbation projections + mask (R0/R1 reused afterwards).
  hipLaunchKernelGGL((gemm16<0, float>), gproj, blk, 0, stream, query, mp_wq_w, mp_wq_b, (void*)R0);
  hipLaunchKernelGGL((gemm16<0, float>), gproj, blk, 0, stream, key,   mp_wk_w, mp_wk_b, (void*)R1);
  hipLaunchKernelGGL(mask16, gmask, blk, 0, stream, R0, R1, outm);
  // Q/K/V projections: Q->R0, K->R1, V->Vt (transposed, in out region).
  hipLaunchKernelGGL((gemm16<0, float>), gproj, blk, 0, stream, query, wq_w, wq_b, (void*)R0);
  hipLaunchKernelGGL((gemm16<0, float>), gproj, blk, 0, stream, key,   wk_w, wk_b, (void*)R1);
  hipLaunchKernelGGL((gemm16<1, float>), gproj, blk, 0, stream, value, wv_w, wv_b, (void*)Vt);
  hipLaunchKernelGGL(gate_kernel, dim3(BL_ / 4), blk, 0, stream, query, gate_w, gate_b, gbuf);
  // Attention: O written in place over Q (R0).
  hipLaunchKernelGGL(attn16, gattn, blk, 0, stream, R0, R1, Vt, outm, gbuf, R0);
  // Final dense: reads attn out (R0) bf16, writes f32 out (overwrites Vt/gbuf).
  hipLaunchKernelGGL((gemm16<2, us16>), gproj, blk, 0, stream, R0, dense_w, dense_b, (void*)out0);
}